// Round 4
// baseline (136.885 us; speedup 1.0000x reference)
//
#include <hip/hip_runtime.h>

// Geometry (fixed by the reference)
#define FDIM 16
#define SDIM 512
#define ODIM 32
#define SF   (SDIM * FDIM)   // 8192 floats per batch row
#define PAIRS 512            // (f,o) pairs; W[s*512 + p], p = f*32+o
#define NB   8               // batches per block (W reuse factor)
#define SC   32              // shifts per block
#define NSC  (SDIM / SC)     // 16 s-chunks
#define NBG  (256 / NB)      // 32 batch groups
#define POISON_BASE 0xAAAAAAAAu  // harness poisons d_ws to 0xAA bytes

// Single fused dispatch. Blocks (bg, sc) compute chunk-maxes for NB batches
// x 512 pairs (W float4 loaded once, reused across NB accumulators), store
// partials to ws, then the LAST block of each bg (device-scope counter,
// poison value as the known initial state) reduces the 16 chunks, f-sums,
// adds bias, relus, writes out. Saves phase2's launch + 8 MB HBM re-read.
__global__ __launch_bounds__(256) void max_layer_fused(
    const float* __restrict__ x, const float* __restrict__ W,
    const float* __restrict__ bias, float* __restrict__ part,
    unsigned* __restrict__ cnt, float* __restrict__ out) {
  __shared__ float xs[NB * SC * FDIM];  // 16 KB: x chunk [b][s][f]
  __shared__ float red[NB * PAIRS];     // 16 KB: th-combine, then finalize
  __shared__ unsigned lastFlag;

  const int t  = threadIdx.x;
  const int bg = blockIdx.x / NSC;
  const int sc = blockIdx.x % NSC;

  // Stage x chunk (coalesced float4).
  const float4* xin = (const float4*)x;
  float4* xs4 = (float4*)xs;
  for (int i = t; i < NB * SC * FDIM / 4; i += 256) {
    int b   = i / (SC * FDIM / 4);
    int off = i % (SC * FDIM / 4);
    xs4[i] = xin[(size_t)(bg * NB + b) * (SF / 4) + sc * (SC * FDIM / 4) + off];
  }
  __syncthreads();

  const int tq = t & 127;   // owns pairs 4tq..4tq+3 (one f)
  const int th = t >> 7;    // s-half 0/1
  const int f  = tq >> 3;

  const float NEG = -3.402823466e+38f;
  float4 macc[NB];
#pragma unroll
  for (int b = 0; b < NB; ++b) macc[b] = make_float4(NEG, NEG, NEG, NEG);

  const float4* wp = (const float4*)W + (size_t)(sc * SC) * (PAIRS / 4) + tq;

#pragma unroll 4
  for (int j = 0; j < SC / 2; ++j) {
    const int s = th * (SC / 2) + j;
    float4 w = wp[s * (PAIRS / 4)];      // contiguous 2KB W row per s
    const float* xp = xs + s * FDIM + f;
#pragma unroll
    for (int b = 0; b < NB; ++b) {
      float xv = xp[b * SC * FDIM];      // LDS broadcast
      macc[b].x = fmaxf(macc[b].x, xv * w.x);
      macc[b].y = fmaxf(macc[b].y, xv * w.y);
      macc[b].z = fmaxf(macc[b].z, xv * w.z);
      macc[b].w = fmaxf(macc[b].w, xv * w.w);
    }
  }

  // Combine the two s-halves; write partials part[(bg*NB+b)*NSC + sc][p].
  if (th == 1) {
#pragma unroll
    for (int b = 0; b < NB; ++b) ((float4*)red)[b * 128 + tq] = macc[b];
  }
  __syncthreads();
  if (th == 0) {
#pragma unroll
    for (int b = 0; b < NB; ++b) {
      float4 o = ((float4*)red)[b * 128 + tq];
      o.x = fmaxf(o.x, macc[b].x);
      o.y = fmaxf(o.y, macc[b].y);
      o.z = fmaxf(o.z, macc[b].z);
      o.w = fmaxf(o.w, macc[b].w);
      ((float4*)part)[((size_t)(bg * NB + b) * NSC + sc) * 128 + tq] = o;
    }
  }

  // Publish partials device-wide, then count completions for this bg.
  __threadfence();            // release: partials visible device-scope
  __syncthreads();
  if (t == 0) {
    unsigned old = atomicAdd(&cnt[bg], 1u);
    // ws is poisoned to 0xAA bytes before every launch; accept a 0 base too.
    lastFlag = ((old - POISON_BASE) == (unsigned)(NSC - 1)) ||
               (old == (unsigned)(NSC - 1));
  }
  __syncthreads();
  if (!lastFlag) return;
  __threadfence();            // acquire: see all other blocks' partials

  // Finalize this bg: max over 16 chunks, then f-sum + bias + relu.
  const int q  = t & 127;   // float4 column within a pair-row
  const int bh = t >> 7;
  const float4* pb = (const float4*)part + (size_t)bg * NB * NSC * 128;
#pragma unroll
  for (int bb = 0; bb < NB / 2; ++bb) {
    const int b = bb * 2 + bh;
    float4 m = pb[(size_t)(b * NSC) * 128 + q];
#pragma unroll
    for (int c = 1; c < NSC; ++c) {
      float4 v = pb[(size_t)(b * NSC + c) * 128 + q];
      m.x = fmaxf(m.x, v.x);
      m.y = fmaxf(m.y, v.y);
      m.z = fmaxf(m.z, v.z);
      m.w = fmaxf(m.w, v.w);
    }
    ((float4*)red)[b * 128 + q] = m;
  }
  __syncthreads();
  {
    const int b = t >> 5, o = t & 31;
    float s = bias[o];
#pragma unroll
    for (int ff = 0; ff < FDIM; ++ff) s += red[b * PAIRS + ff * ODIM + o];
    out[(bg * NB + b) * ODIM + o] = fmaxf(s, 0.0f);
  }
}

extern "C" void kernel_launch(void* const* d_in, const int* in_sizes, int n_in,
                              void* d_out, int out_size, void* d_ws, size_t ws_size,
                              hipStream_t stream) {
  const float* x    = (const float*)d_in[0];
  const float* W    = (const float*)d_in[1];
  const float* bias = (const float*)d_in[2];
  float* out        = (float*)d_out;
  float* part       = (float*)d_ws;                      // 8 MB partials
  unsigned* cnt     = (unsigned*)((char*)d_ws + (size_t)NBG * NB * NSC * PAIRS * 4);

  max_layer_fused<<<dim3(NBG * NSC), dim3(256), 0, stream>>>(x, W, bias, part, cnt, out);
}

// Round 5
// 71.182 us; speedup vs baseline: 1.9230x; 1.9230x over previous
//
#include <hip/hip_runtime.h>

// Geometry (fixed by the reference)
#define FDIM 16
#define SDIM 512
#define ODIM 32
#define SF   (SDIM * FDIM)   // 8192 floats per batch row
#define PAIRS 512            // (f,o) pairs; W[s*512 + p], p = f*32+o
#define NB   8               // batches per block (W reuse factor)
#define SC   32              // shifts per block
#define NSC  (SDIM / SC)     // 16 s-chunks
#define NBG  (256 / NB)      // 32 batch groups

// NOTE (R4 post-mortem): do NOT fuse these with device-scope fences.
// __threadfence() on gfx950 = buffer_wbl2/inv across non-coherent XCD L2s;
// 512 blocks x fence = ~90 us of stall. The kernel boundary IS the cheap
// device-wide sync here.

// Phase 1: per (bg, sc) block: chunk-max over SC shifts for NB batches x all
// 512 pairs. Each W float4 is loaded once and reused across NB accumulators
// -> W L2 traffic = 256/NB = 32 MB. Inner loop processes two s per step so
// fmaxf(m, fmaxf(p0,p1)) emits v_max3_f32 (3 VALU / 2 products, not 4).
__global__ __launch_bounds__(256) void max_layer_phase1(
    const float* __restrict__ x, const float* __restrict__ W,
    float* __restrict__ part) {
  __shared__ float xs[NB * SC * FDIM];  // 16 KB, [b][s][f]
  __shared__ float red[NB * PAIRS];     // 16 KB, th=1 partials

  const int t  = threadIdx.x;
  const int bg = blockIdx.x / NSC;
  const int sc = blockIdx.x % NSC;

  // Stage x chunk (coalesced float4).
  const float4* xin = (const float4*)x;
  float4* xs4 = (float4*)xs;
  for (int i = t; i < NB * SC * FDIM / 4; i += 256) {
    int b   = i / (SC * FDIM / 4);
    int off = i % (SC * FDIM / 4);
    xs4[i] = xin[(size_t)(bg * NB + b) * (SF / 4) + sc * (SC * FDIM / 4) + off];
  }
  __syncthreads();

  const int tq = t & 127;   // owns pairs 4tq..4tq+3 (one f)
  const int th = t >> 7;    // s-half 0/1
  const int f  = tq >> 3;

  const float NEG = -3.402823466e+38f;
  float4 macc[NB];
#pragma unroll
  for (int b = 0; b < NB; ++b) macc[b] = make_float4(NEG, NEG, NEG, NEG);

  const float4* wp = (const float4*)W + (size_t)(sc * SC) * (PAIRS / 4) + tq;

#pragma unroll 4
  for (int j = 0; j < SC / 2; j += 2) {
    const int s0 = th * (SC / 2) + j;
    float4 w0 = wp[s0 * (PAIRS / 4)];
    float4 w1 = wp[(s0 + 1) * (PAIRS / 4)];
    const float* xp = xs + s0 * FDIM + f;
#pragma unroll
    for (int b = 0; b < NB; ++b) {
      float xv0 = xp[b * SC * FDIM];          // LDS broadcast
      float xv1 = xp[b * SC * FDIM + FDIM];
      macc[b].x = fmaxf(macc[b].x, fmaxf(xv0 * w0.x, xv1 * w1.x));  // v_max3
      macc[b].y = fmaxf(macc[b].y, fmaxf(xv0 * w0.y, xv1 * w1.y));
      macc[b].z = fmaxf(macc[b].z, fmaxf(xv0 * w0.z, xv1 * w1.z));
      macc[b].w = fmaxf(macc[b].w, fmaxf(xv0 * w0.w, xv1 * w1.w));
    }
  }

  // Combine the two s-halves; write partials part[(bg*NB+b)*NSC + sc][p].
  if (th == 1) {
#pragma unroll
    for (int b = 0; b < NB; ++b) ((float4*)red)[b * 128 + tq] = macc[b];
  }
  __syncthreads();
  if (th == 0) {
#pragma unroll
    for (int b = 0; b < NB; ++b) {
      float4 o = ((float4*)red)[b * 128 + tq];
      o.x = fmaxf(o.x, macc[b].x);
      o.y = fmaxf(o.y, macc[b].y);
      o.z = fmaxf(o.z, macc[b].z);
      o.w = fmaxf(o.w, macc[b].w);
      ((float4*)part)[((size_t)(bg * NB + b) * NSC + sc) * 128 + tq] = o;
    }
  }
}

// Phase 2: one block per batch; float4 merge of the 16 chunk-partials,
// then f-sum + bias + relu.
__global__ __launch_bounds__(128) void max_layer_phase2(
    const float* __restrict__ part, const float* __restrict__ bias,
    float* __restrict__ out) {
  __shared__ float red[PAIRS];
  const int t = threadIdx.x;
  const int b = blockIdx.x;
  const float4* pb = (const float4*)part + (size_t)b * NSC * 128;

  float4 m = pb[t];
#pragma unroll
  for (int c = 1; c < NSC; c += 2) {
    float4 v0 = pb[c * 128 + t];
    float4 v1 = pb[(c + 1 < NSC ? c + 1 : c) * 128 + t];
    m.x = fmaxf(m.x, fmaxf(v0.x, v1.x));
    m.y = fmaxf(m.y, fmaxf(v0.y, v1.y));
    m.z = fmaxf(m.z, fmaxf(v0.z, v1.z));
    m.w = fmaxf(m.w, fmaxf(v0.w, v1.w));
  }
  ((float4*)red)[t] = m;
  __syncthreads();

  if (t < ODIM) {
    float s = bias[t];
#pragma unroll
    for (int ff = 0; ff < FDIM; ++ff) s += red[ff * ODIM + t];
    out[b * ODIM + t] = fmaxf(s, 0.0f);
  }
}

extern "C" void kernel_launch(void* const* d_in, const int* in_sizes, int n_in,
                              void* d_out, int out_size, void* d_ws, size_t ws_size,
                              hipStream_t stream) {
  const float* x    = (const float*)d_in[0];
  const float* W    = (const float*)d_in[1];
  const float* bias = (const float*)d_in[2];
  float* out        = (float*)d_out;
  float* part       = (float*)d_ws;   // 256*16*512*4 = 8 MB scratch

  max_layer_phase1<<<dim3(NBG * NSC), dim3(256), 0, stream>>>(x, W, part);
  max_layer_phase2<<<dim3(256), dim3(128), 0, stream>>>(part, bias, out);
}